// Round 1
// baseline (211.485 us; speedup 1.0000x reference)
//
#include <hip/hip_runtime.h>
#include <hip/hip_bf16.h>
#include <math.h>

// N-BEATS SeasonalityBlock, bf16 MFMA pipeline.
// B=16384, UNITS=512, THETAS=128, Lb=512, Lf=128.

#define BATCH 16384
#define UNITS 512
#define TDIM  128
#define LB    512
#define LF    128

typedef __bf16 bf16x8 __attribute__((ext_vector_type(8)));
typedef float  f32x4  __attribute__((ext_vector_type(4)));

__device__ __forceinline__ unsigned short f2bf(float f) {
  union { float f; unsigned u; } v; v.f = f;
  unsigned r = v.u + 0x7fff + ((v.u >> 16) & 1);   // RTNE
  return (unsigned short)(r >> 16);
}

__device__ __forceinline__ void async_copy16(const void* g, void* l) {
  __builtin_amdgcn_global_load_lds(
      (const __attribute__((address_space(1))) unsigned int*)g,
      (__attribute__((address_space(3))) unsigned int*)l,
      16, 0, 0);
}

// ---------------- conversion kernels ----------------

__global__ void cvt_f32_bf16(const float* __restrict__ src,
                             unsigned short* __restrict__ dst, int n8) {
  int i = blockIdx.x * blockDim.x + threadIdx.x;
  if (i >= n8) return;
  const float4* s = (const float4*)src;
  float4 a = s[2 * i], b = s[2 * i + 1];
  uint4 o;
  o.x = (unsigned)f2bf(a.x) | ((unsigned)f2bf(a.y) << 16);
  o.y = (unsigned)f2bf(a.z) | ((unsigned)f2bf(a.w) << 16);
  o.z = (unsigned)f2bf(b.x) | ((unsigned)f2bf(b.y) << 16);
  o.w = (unsigned)f2bf(b.z) | ((unsigned)f2bf(b.w) << 16);
  ((uint4*)dst)[i] = o;
}

// basis_bT [512][128], basis_fT [128][128]; bT[l][r] = (r even ? cos : sin)((r>>1) * 2*pi*l/L)
__global__ void gen_basis(unsigned short* __restrict__ bT,
                          unsigned short* __restrict__ fT) {
  int idx = blockIdx.x * blockDim.x + threadIdx.x;
  if (idx < LB * TDIM) {
    int l = idx >> 7, r = idx & 127;
    float t = 6.283185307179586f * (float)l / (float)LB;
    float ang = (float)(r >> 1) * t;
    bT[idx] = f2bf((r & 1) ? sinf(ang) : cosf(ang));
  } else if (idx < LB * TDIM + LF * TDIM) {
    int j = idx - LB * TDIM;
    int l = j >> 7, r = j & 127;
    float t = 6.283185307179586f * (float)l / (float)LF;
    float ang = (float)(r >> 1) * t;
    fT[j] = f2bf((r & 1) ? sinf(ang) : cosf(ang));
  }
}

// ---------------- GEMM: C = act(A[M,K] @ W[N,K]^T + bias) ----------------
// 128x128 tile, BK=64, 256 threads = 4 waves in 2x2, each wave 64x64 (4x4 frags
// of 16x16), mfma_f32_16x16x32_bf16, global_load_lds width-16 staging (m97).

template <bool RELU, bool BIAS, bool OUT_BF16>
__global__ __launch_bounds__(256) void gemm_bt(
    const unsigned short* __restrict__ A,   // [M,K] bf16
    const unsigned short* __restrict__ W,   // [N,K] bf16
    const float* __restrict__ bias,         // [N] fp32 or null
    void* __restrict__ Cout,                // [M,N] bf16 or f32
    int M, int N, int K) {
  __shared__ __align__(16) unsigned short As[128 * 64];
  __shared__ __align__(16) unsigned short Ws[128 * 64];

  const int tid  = threadIdx.x;
  const int lane = tid & 63;
  const int wave = tid >> 6;
  const int wr = wave >> 1, wc = wave & 1;
  const int brow = blockIdx.y << 7;
  const int bcol = blockIdx.x << 7;

  f32x4 acc[4][4];
#pragma unroll
  for (int m = 0; m < 4; ++m)
#pragma unroll
    for (int n = 0; n < 4; ++n) acc[m][n] = (f32x4){0.f, 0.f, 0.f, 0.f};

  const int r8 = tid >> 3;        // row-within-32-row-chunk
  const int c8 = (tid & 7) * 8;   // k-element offset (8 elems = 16B)

  for (int k0 = 0; k0 < K; k0 += 64) {
#pragma unroll
    for (int i = 0; i < 4; ++i) {
      const unsigned short* ga = A + (size_t)(brow + i * 32 + r8) * K + k0 + c8;
      async_copy16(ga, (char*)As + i * 4096 + tid * 16);
      const unsigned short* gw = W + (size_t)(bcol + i * 32 + r8) * K + k0 + c8;
      async_copy16(gw, (char*)Ws + i * 4096 + tid * 16);
    }
    __syncthreads();

#pragma unroll
    for (int kk = 0; kk < 2; ++kk) {
      bf16x8 av[4], wv[4];
#pragma unroll
      for (int m = 0; m < 4; ++m)
        av[m] = *(const bf16x8*)(As + (size_t)(wr * 64 + m * 16 + (lane & 15)) * 64 +
                                 (lane >> 4) * 8 + kk * 32);
#pragma unroll
      for (int n = 0; n < 4; ++n)
        wv[n] = *(const bf16x8*)(Ws + (size_t)(wc * 64 + n * 16 + (lane & 15)) * 64 +
                                 (lane >> 4) * 8 + kk * 32);
#pragma unroll
      for (int m = 0; m < 4; ++m)
#pragma unroll
        for (int n = 0; n < 4; ++n)
          acc[m][n] = __builtin_amdgcn_mfma_f32_16x16x32_bf16(av[m], wv[n], acc[m][n], 0, 0, 0);
    }
    __syncthreads();
  }

  // epilogue: C/D layout col = lane&15, row = (lane>>4)*4 + reg
  const int lrow = (lane >> 4) * 4;
  const int lcol = lane & 15;
#pragma unroll
  for (int n = 0; n < 4; ++n) {
    const int col = bcol + wc * 64 + n * 16 + lcol;
    float bv = 0.f;
    if (BIAS) bv = bias[col];
#pragma unroll
    for (int m = 0; m < 4; ++m) {
      const int row0 = brow + wr * 64 + m * 16 + lrow;
#pragma unroll
      for (int r = 0; r < 4; ++r) {
        float v = acc[m][n][r] + bv;
        if (RELU) v = fmaxf(v, 0.f);
        if (OUT_BF16)
          ((unsigned short*)Cout)[(size_t)(row0 + r) * N + col] = f2bf(v);
        else
          ((float*)Cout)[(size_t)(row0 + r) * N + col] = v;
      }
    }
  }
}

// ---------------- launch ----------------

extern "C" void kernel_launch(void* const* d_in, const int* in_sizes, int n_in,
                              void* d_out, int out_size, void* d_ws, size_t ws_size,
                              hipStream_t stream) {
  const float* x  = (const float*)d_in[0];
  const float* W1 = (const float*)d_in[1];
  const float* b1 = (const float*)d_in[2];
  const float* W2 = (const float*)d_in[3];
  const float* b2 = (const float*)d_in[4];
  const float* W3 = (const float*)d_in[5];
  const float* b3 = (const float*)d_in[6];
  const float* W4 = (const float*)d_in[7];
  const float* b4 = (const float*)d_in[8];
  const float* Wt = (const float*)d_in[9];

  char* ws = (char*)d_ws;
  unsigned short* buf0   = (unsigned short*)ws;                       // 16 MB
  unsigned short* buf1   = (unsigned short*)(ws + (16u << 20));       // 16 MB
  unsigned short* thetab = (unsigned short*)(ws + (32u << 20));       // 4 MB
  unsigned short* W1b    = (unsigned short*)(ws + (36u << 20));
  unsigned short* W2b    = W1b + UNITS * UNITS;
  unsigned short* W3b    = W2b + UNITS * UNITS;
  unsigned short* W4b    = W3b + UNITS * UNITS;
  unsigned short* Wtb    = W4b + UNITS * UNITS;
  unsigned short* basb   = Wtb + TDIM * UNITS;   // [512][128]
  unsigned short* basf   = basb + LB * TDIM;     // [128][128]

  // conversions
  cvt_f32_bf16<<<(BATCH * UNITS / 8 + 255) / 256, 256, 0, stream>>>(x, buf0, BATCH * UNITS / 8);
  cvt_f32_bf16<<<(UNITS * UNITS / 8 + 255) / 256, 256, 0, stream>>>(W1, W1b, UNITS * UNITS / 8);
  cvt_f32_bf16<<<(UNITS * UNITS / 8 + 255) / 256, 256, 0, stream>>>(W2, W2b, UNITS * UNITS / 8);
  cvt_f32_bf16<<<(UNITS * UNITS / 8 + 255) / 256, 256, 0, stream>>>(W3, W3b, UNITS * UNITS / 8);
  cvt_f32_bf16<<<(UNITS * UNITS / 8 + 255) / 256, 256, 0, stream>>>(W4, W4b, UNITS * UNITS / 8);
  cvt_f32_bf16<<<(TDIM * UNITS / 8 + 255) / 256, 256, 0, stream>>>(Wt, Wtb, TDIM * UNITS / 8);
  gen_basis<<<(LB * TDIM + LF * TDIM + 255) / 256, 256, 0, stream>>>(basb, basf);

  // 4 FC+ReLU layers
  gemm_bt<true, true, true><<<dim3(UNITS / 128, BATCH / 128), 256, 0, stream>>>(
      buf0, W1b, b1, buf1, BATCH, UNITS, UNITS);
  gemm_bt<true, true, true><<<dim3(UNITS / 128, BATCH / 128), 256, 0, stream>>>(
      buf1, W2b, b2, buf0, BATCH, UNITS, UNITS);
  gemm_bt<true, true, true><<<dim3(UNITS / 128, BATCH / 128), 256, 0, stream>>>(
      buf0, W3b, b3, buf1, BATCH, UNITS, UNITS);
  gemm_bt<true, true, true><<<dim3(UNITS / 128, BATCH / 128), 256, 0, stream>>>(
      buf1, W4b, b4, buf0, BATCH, UNITS, UNITS);

  // theta = h4 @ Wt^T  (bf16 out)
  gemm_bt<false, false, true><<<dim3(TDIM / 128, BATCH / 128), 256, 0, stream>>>(
      buf0, Wtb, nullptr, thetab, BATCH, TDIM, UNITS);

  // backcast / forecast (fp32 out, straight to d_out)
  float* out = (float*)d_out;
  gemm_bt<false, false, false><<<dim3(LB / 128, BATCH / 128), 256, 0, stream>>>(
      thetab, basb, nullptr, out, BATCH, LB, TDIM);
  gemm_bt<false, false, false><<<dim3(LF / 128, BATCH / 128), 256, 0, stream>>>(
      thetab, basf, nullptr, out + (size_t)BATCH * LB, BATCH, LF, TDIM);
}

// Round 2
// 176.810 us; speedup vs baseline: 1.1961x; 1.1961x over previous
//
#include <hip/hip_runtime.h>
#include <hip/hip_bf16.h>
#include <math.h>

// N-BEATS SeasonalityBlock, fully fused persistent kernel.
// B=16384, UNITS=512, THETAS=128, Lb=512, Lf=128.
// 256 blocks x 512 threads (8 waves); each block owns 64 batch rows.
// h[64][512] bf16 in 64KB LDS (XOR-swizzled); weights read from L2.

#define BATCH 16384
#define ROWS  64

typedef __bf16 bf16x8 __attribute__((ext_vector_type(8)));
typedef float  f32x4  __attribute__((ext_vector_type(4)));

__device__ __forceinline__ unsigned short f2bf(float f) {
  union { float f; unsigned u; } v; v.f = f;
  unsigned r = v.u + 0x7fff + ((v.u >> 16) & 1);   // RTNE
  return (unsigned short)(r >> 16);
}

// ---------------- prep: weights fp32->bf16 + basis tables (one launch) ----
// converts: W1..W4 (4 x 262144 fp32), Wt (65536 fp32), 8 elems/thread
//   -> threads [0, 139264)
// basis:    bas[640*128] bf16  (backcast 512x128 then forecast 128x128)
//   -> threads [139264, 221184)
__global__ __launch_bounds__(256) void prep_kernel(
    const float* __restrict__ W1, const float* __restrict__ W2,
    const float* __restrict__ W3, const float* __restrict__ W4,
    const float* __restrict__ Wt,
    unsigned short* __restrict__ W1b, unsigned short* __restrict__ W2b,
    unsigned short* __restrict__ W3b, unsigned short* __restrict__ W4b,
    unsigned short* __restrict__ Wtb,
    unsigned short* __restrict__ bas) {
  const int tid = blockIdx.x * 256 + threadIdx.x;
  if (tid < 139264) {
    const float* src; unsigned short* dst; int loc;
    if (tid < 131072) {
      const int w = tid >> 15; loc = tid & 32767;
      src = (w == 0) ? W1 : (w == 1) ? W2 : (w == 2) ? W3 : W4;
      dst = (w == 0) ? W1b : (w == 1) ? W2b : (w == 2) ? W3b : W4b;
    } else {
      src = Wt; dst = Wtb; loc = tid - 131072;
    }
    const float4* s = (const float4*)src;
    const float4 a = s[2 * loc], b = s[2 * loc + 1];
    uint4 o;
    o.x = f2bf(a.x) | ((unsigned)f2bf(a.y) << 16);
    o.y = f2bf(a.z) | ((unsigned)f2bf(a.w) << 16);
    o.z = f2bf(b.x) | ((unsigned)f2bf(b.y) << 16);
    o.w = f2bf(b.z) | ((unsigned)f2bf(b.w) << 16);
    ((uint4*)dst)[loc] = o;
  } else {
    const int j = tid - 139264;
    int l, r, L;
    if (j < 65536) { l = j >> 7; r = j & 127; L = 512; }
    else           { const int k = j - 65536; l = k >> 7; r = k & 127; L = 128; }
    const float ang = (float)(r >> 1) * 6.283185307179586f * (float)l / (float)L;
    bas[j] = f2bf((r & 1) ? sinf(ang) : cosf(ang));
  }
}

// ---------------- fused layer: h = relu(h @ W^T + b), in place -----------
// h: LDS [64][512] bf16, row stride 1024B, byte-swizzle (kbyte ^ ((row&7)<<4)).
// Wave wv owns output cols [wv*64, wv*64+64). B-frags straight from global (L2).
__device__ __forceinline__ void layer512(
    unsigned short* h, const unsigned short* __restrict__ W,
    const float* __restrict__ bias, int wv, int lane) {
  const int l15 = lane & 15, g = lane >> 4;
  f32x4 acc[4][4];
#pragma unroll
  for (int m = 0; m < 4; ++m)
#pragma unroll
    for (int n = 0; n < 4; ++n) acc[m][n] = (f32x4){0.f, 0.f, 0.f, 0.f};

  int rb[4], am[4];
#pragma unroll
  for (int m = 0; m < 4; ++m) {
    const int row = m * 16 + l15;
    rb[m] = row * 1024;
    am[m] = (row & 7) << 4;
  }
  const unsigned short* bp[4];
#pragma unroll
  for (int n = 0; n < 4; ++n)
    bp[n] = W + (size_t)(wv * 64 + n * 16 + l15) * 512 + g * 8;

  bf16x8 bvc[4];
#pragma unroll
  for (int n = 0; n < 4; ++n) bvc[n] = *(const bf16x8*)bp[n];

#pragma unroll
  for (int ks = 0; ks < 16; ++ks) {
    bf16x8 bvn[4];
    if (ks < 15) {
#pragma unroll
      for (int n = 0; n < 4; ++n) bvn[n] = *(const bf16x8*)(bp[n] + (ks + 1) * 32);
    }
    bf16x8 av[4];
    const int kb = ks * 64 + g * 16;
#pragma unroll
    for (int m = 0; m < 4; ++m)
      av[m] = *(const bf16x8*)((const char*)h + rb[m] + (kb ^ am[m]));
#pragma unroll
    for (int m = 0; m < 4; ++m)
#pragma unroll
      for (int n = 0; n < 4; ++n)
        acc[m][n] = __builtin_amdgcn_mfma_f32_16x16x32_bf16(av[m], bvc[n], acc[m][n], 0, 0, 0);
    if (ks < 15) {
#pragma unroll
      for (int n = 0; n < 4; ++n) bvc[n] = bvn[n];
    }
  }

  __syncthreads();   // all reads of h complete before in-place overwrite
#pragma unroll
  for (int n = 0; n < 4; ++n) {
    const int col = wv * 64 + n * 16 + l15;
    const float bv = bias[col];
#pragma unroll
    for (int m = 0; m < 4; ++m)
#pragma unroll
      for (int r = 0; r < 4; ++r) {
        const int row = m * 16 + g * 4 + r;
        const float v = fmaxf(acc[m][n][r] + bv, 0.f);
        *(unsigned short*)((char*)h + row * 1024 + ((col * 2) ^ ((row & 7) << 4))) = f2bf(v);
      }
  }
  __syncthreads();   // writes visible
}

// ---------------- fused mega-kernel --------------------------------------
__global__ __launch_bounds__(512, 2) void fused_nbeats(
    const float* __restrict__ x,
    const unsigned short* __restrict__ W1, const float* __restrict__ b1,
    const unsigned short* __restrict__ W2, const float* __restrict__ b2,
    const unsigned short* __restrict__ W3, const float* __restrict__ b3,
    const unsigned short* __restrict__ W4, const float* __restrict__ b4,
    const unsigned short* __restrict__ Wt,
    const unsigned short* __restrict__ bas,
    float* __restrict__ out) {
  __shared__ __align__(16) unsigned short hA[ROWS * 512];   // 64 KB

  const int tid  = threadIdx.x;
  const int lane = tid & 63;
  const int wv   = tid >> 6;
  const int l15  = lane & 15, g = lane >> 4;
  const int r0   = blockIdx.x * ROWS;

  // ---- phase 0: x fp32 -> hA bf16 (swizzled) ----
  {
    const float4* xs = (const float4*)(x + (size_t)r0 * 512);
#pragma unroll
    for (int j = 0; j < 16; ++j) {
      const int f = tid + j * 512;          // float4 index in [64][128]
      const int row = f >> 7, c4 = f & 127;
      const float4 v = xs[f];
      uint2 o;
      o.x = f2bf(v.x) | ((unsigned)f2bf(v.y) << 16);
      o.y = f2bf(v.z) | ((unsigned)f2bf(v.w) << 16);
      *(uint2*)((char*)hA + row * 1024 + ((c4 * 8) ^ ((row & 7) << 4))) = o;
    }
  }
  __syncthreads();

  // ---- 4 FC+ReLU layers, in place ----
  layer512(hA, W1, b1, wv, lane);
  layer512(hA, W2, b2, wv, lane);
  layer512(hA, W3, b3, wv, lane);
  layer512(hA, W4, b4, wv, lane);

  // ---- theta = h4 @ Wt^T  (128 cols; wave wv -> cols wv*16..+15) ----
  {
    f32x4 tacc[4];
#pragma unroll
    for (int m = 0; m < 4; ++m) tacc[m] = (f32x4){0.f, 0.f, 0.f, 0.f};
    int rb[4], am[4];
#pragma unroll
    for (int m = 0; m < 4; ++m) {
      const int row = m * 16 + l15;
      rb[m] = row * 1024;
      am[m] = (row & 7) << 4;
    }
    const unsigned short* tp = Wt + (size_t)(wv * 16 + l15) * 512 + g * 8;
    bf16x8 bc = *(const bf16x8*)tp;
#pragma unroll
    for (int ks = 0; ks < 16; ++ks) {
      bf16x8 bn;
      if (ks < 15) bn = *(const bf16x8*)(tp + (ks + 1) * 32);
      bf16x8 av[4];
      const int kb = ks * 64 + g * 16;
#pragma unroll
      for (int m = 0; m < 4; ++m)
        av[m] = *(const bf16x8*)((const char*)hA + rb[m] + (kb ^ am[m]));
#pragma unroll
      for (int m = 0; m < 4; ++m)
        tacc[m] = __builtin_amdgcn_mfma_f32_16x16x32_bf16(av[m], bc, tacc[m], 0, 0, 0);
      if (ks < 15) bc = bn;
    }
    __syncthreads();   // h4 reads done; theta overwrites hA[0:16KB]
    // theta -> hA as [64][128] bf16, row stride 256B, same swizzle
#pragma unroll
    for (int m = 0; m < 4; ++m)
#pragma unroll
      for (int r = 0; r < 4; ++r) {
        const int row = m * 16 + g * 4 + r;
        const int col = wv * 16 + l15;
        *(unsigned short*)((char*)hA + row * 256 + ((col * 2) ^ ((row & 7) << 4))) =
            f2bf(tacc[m][r]);
      }
  }
  __syncthreads();

  // ---- backcast/forecast: out = theta @ basT^T, basT = [640][128] bf16 ----
  // wave wv -> output cols [wv*80, wv*80+80): 5 frags of 16.
  {
    f32x4 facc[4][5];
#pragma unroll
    for (int m = 0; m < 4; ++m)
#pragma unroll
      for (int n = 0; n < 5; ++n) facc[m][n] = (f32x4){0.f, 0.f, 0.f, 0.f};
    int rb[4], am[4];
#pragma unroll
    for (int m = 0; m < 4; ++m) {
      const int row = m * 16 + l15;
      rb[m] = row * 256;
      am[m] = (row & 7) << 4;
    }
    const unsigned short* fp0 = bas + (size_t)(wv * 80 + l15) * 128 + g * 8;
#pragma unroll
    for (int ks = 0; ks < 4; ++ks) {
      bf16x8 av[4];
      const int kb = ks * 64 + g * 16;
#pragma unroll
      for (int m = 0; m < 4; ++m)
        av[m] = *(const bf16x8*)((const char*)hA + rb[m] + (kb ^ am[m]));
#pragma unroll
      for (int n = 0; n < 5; ++n) {
        const bf16x8 bv = *(const bf16x8*)(fp0 + (size_t)(n * 16) * 128 + ks * 32);
#pragma unroll
        for (int m = 0; m < 4; ++m)
          facc[m][n] = __builtin_amdgcn_mfma_f32_16x16x32_bf16(av[m], bv, facc[m][n], 0, 0, 0);
      }
    }
    // write fp32 output: backcast [16384][512] then forecast [16384][128]
#pragma unroll
    for (int n = 0; n < 5; ++n) {
      const int col = wv * 80 + n * 16 + l15;
#pragma unroll
      for (int m = 0; m < 4; ++m)
#pragma unroll
        for (int r = 0; r < 4; ++r) {
          const int row = r0 + m * 16 + g * 4 + r;
          const float v = facc[m][n][r];
          if (col < 512)
            out[(size_t)row * 512 + col] = v;
          else
            out[(size_t)BATCH * 512 + (size_t)row * 128 + (col - 512)] = v;
        }
    }
  }
}

// ---------------- launch --------------------------------------------------
extern "C" void kernel_launch(void* const* d_in, const int* in_sizes, int n_in,
                              void* d_out, int out_size, void* d_ws, size_t ws_size,
                              hipStream_t stream) {
  const float* x  = (const float*)d_in[0];
  const float* W1 = (const float*)d_in[1];
  const float* b1 = (const float*)d_in[2];
  const float* W2 = (const float*)d_in[3];
  const float* b2 = (const float*)d_in[4];
  const float* W3 = (const float*)d_in[5];
  const float* b3 = (const float*)d_in[6];
  const float* W4 = (const float*)d_in[7];
  const float* b4 = (const float*)d_in[8];
  const float* Wt = (const float*)d_in[9];

  unsigned short* ws  = (unsigned short*)d_ws;
  unsigned short* W1b = ws;                       // 262144 elems each
  unsigned short* W2b = ws + 262144;
  unsigned short* W3b = ws + 524288;
  unsigned short* W4b = ws + 786432;
  unsigned short* Wtb = ws + 1048576;             // 65536
  unsigned short* bas = ws + 1114112;             // 640*128 = 81920

  prep_kernel<<<864, 256, 0, stream>>>(W1, W2, W3, W4, Wt,
                                       W1b, W2b, W3b, W4b, Wtb, bas);
  fused_nbeats<<<BATCH / ROWS, 512, 0, stream>>>(
      x, W1b, b1, W2b, b2, W3b, b3, W4b, b4, Wtb, bas, (float*)d_out);
}

// Round 3
// 175.451 us; speedup vs baseline: 1.2054x; 1.0077x over previous
//
#include <hip/hip_runtime.h>
#include <hip/hip_bf16.h>
#include <math.h>

// N-BEATS SeasonalityBlock, fused persistent kernel with T3-style
// global_load_lds double-buffered W pipeline.
// B=16384, UNITS=512, THETAS=128, Lb=512, Lf=128.
// 256 blocks x 512 threads (8 waves); each block owns 64 batch rows.
// h[64][512] bf16 (64KB, XOR-swizzled) + 2x32KB W-chunk buffers = 128KB LDS.

#define BATCH 16384
#define ROWS  64

typedef __bf16 bf16x8 __attribute__((ext_vector_type(8)));
typedef float  f32x4  __attribute__((ext_vector_type(4)));

__device__ __forceinline__ unsigned short f2bf(float f) {
  union { float f; unsigned u; } v; v.f = f;
  unsigned r = v.u + 0x7fff + ((v.u >> 16) & 1);   // RTNE
  return (unsigned short)(r >> 16);
}

__device__ __forceinline__ void async_copy16(const void* g, void* l) {
  __builtin_amdgcn_global_load_lds(
      (const __attribute__((address_space(1))) unsigned int*)g,
      (__attribute__((address_space(3))) unsigned int*)l,
      16, 0, 0);
}

// ---------------- prep ----------------------------------------------------
// Layer weights -> K-chunked bf16: Wc[c][col][k'] = W[col][c*32+k'],
//   c in [0,16), col in [0,512), k' in [0,32).  (Wt: col in [0,128).)
// Basis tables bas[640*128] bf16 (backcast 512x128 then forecast 128x128).
__global__ __launch_bounds__(256) void prep_kernel(
    const float* __restrict__ W1, const float* __restrict__ W2,
    const float* __restrict__ W3, const float* __restrict__ W4,
    const float* __restrict__ Wt,
    unsigned short* __restrict__ W1c, unsigned short* __restrict__ W2c,
    unsigned short* __restrict__ W3c, unsigned short* __restrict__ W4c,
    unsigned short* __restrict__ Wtc,
    unsigned short* __restrict__ bas) {
  const int t = blockIdx.x * 256 + threadIdx.x;
  if (t < 139264) {
    const float* src; unsigned short* dst; int u, cshift;
    if (t < 131072) {
      const int w = t >> 15; u = t & 32767; cshift = 11;   // 2048 u per chunk
      src = (w == 0) ? W1 : (w == 1) ? W2 : (w == 2) ? W3 : W4;
      dst = (w == 0) ? W1c : (w == 1) ? W2c : (w == 2) ? W3c : W4c;
    } else {
      u = t - 131072; cshift = 9;                          // 512 u per chunk
      src = Wt; dst = Wtc;
    }
    const int c   = u >> cshift;
    const int rem = u & ((1 << cshift) - 1);
    const int col = rem >> 2;
    const int k0  = (rem & 3) * 8;
    const float4* s = (const float4*)(src + (size_t)col * 512 + c * 32 + k0);
    const float4 a = s[0], b = s[1];
    uint4 o;
    o.x = f2bf(a.x) | ((unsigned)f2bf(a.y) << 16);
    o.y = f2bf(a.z) | ((unsigned)f2bf(a.w) << 16);
    o.z = f2bf(b.x) | ((unsigned)f2bf(b.y) << 16);
    o.w = f2bf(b.z) | ((unsigned)f2bf(b.w) << 16);
    ((uint4*)dst)[u] = o;
  } else if (t < 221184) {
    const int j = t - 139264;
    int l, r, L;
    if (j < 65536) { l = j >> 7; r = j & 127; L = 512; }
    else           { const int k = j - 65536; l = k >> 7; r = k & 127; L = 128; }
    const float ang = (float)(r >> 1) * 6.283185307179586f * (float)l / (float)L;
    bas[j] = f2bf((r & 1) ? sinf(ang) : cosf(ang));
  }
}

// ---------------- fused mega-kernel --------------------------------------
__global__ __launch_bounds__(512, 2) void fused_nbeats(
    const float* __restrict__ x,
    const unsigned short* __restrict__ W1c, const float* __restrict__ b1,
    const unsigned short* __restrict__ W2c, const float* __restrict__ b2,
    const unsigned short* __restrict__ W3c, const float* __restrict__ b3,
    const unsigned short* __restrict__ W4c, const float* __restrict__ b4,
    const unsigned short* __restrict__ Wtc,
    const unsigned short* __restrict__ bas,
    float* __restrict__ out) {
  __shared__ __align__(16) unsigned short hA[ROWS * 512];   // 64 KB
  __shared__ __align__(16) unsigned short Wc[2][16384];     // 2 x 32 KB

  const int tid  = threadIdx.x;
  const int lane = tid & 63;
  const int wv   = tid >> 6;
  const int l15  = lane & 15, g = lane >> 4;
  const int r0   = blockIdx.x * ROWS;

  const unsigned short* Ws[4] = {W1c, W2c, W3c, W4c};
  const float* bs[4] = {b1, b2, b3, b4};

  // A-frag addressing constants (h rows 1024B, XOR swizzle (row&7)<<4)
  int rb[4], am[4];
#pragma unroll
  for (int m = 0; m < 4; ++m) {
    const int row = m * 16 + l15;
    rb[m] = row * 1024;
    am[m] = (row & 7) << 4;
  }

  // ---- issue W1 chunk 0 DMA first (overlaps x phase) ----
  {
    const char* gp = (const char*)W1c;
#pragma unroll
    for (int j = 0; j < 4; ++j) {
      const int off = wv * 4096 + j * 1024 + lane * 16;
      async_copy16(gp + off, (char*)Wc[0] + off);
    }
  }

  // ---- phase 0: x fp32 -> hA bf16 (swizzled) ----
  {
    const float4* xs = (const float4*)(x + (size_t)r0 * 512);
#pragma unroll
    for (int j = 0; j < 16; ++j) {
      const int f = tid + j * 512;          // float4 index in [64][128]
      const int row = f >> 7, c4 = f & 127;
      const float4 v = xs[f];
      uint2 o;
      o.x = f2bf(v.x) | ((unsigned)f2bf(v.y) << 16);
      o.y = f2bf(v.z) | ((unsigned)f2bf(v.w) << 16);
      *(uint2*)((char*)hA + row * 1024 + ((c4 * 8) ^ ((row & 7) << 4))) = o;
    }
  }
  __syncthreads();   // drains x-writes AND W1 chunk-0 DMA

  // ---- 4 FC+ReLU layers, chunked-DMA pipeline ----
#pragma unroll 1
  for (int L = 0; L < 4; ++L) {
    f32x4 acc[4][4];
#pragma unroll
    for (int m = 0; m < 4; ++m)
#pragma unroll
      for (int n = 0; n < 4; ++n) acc[m][n] = (f32x4){0.f, 0.f, 0.f, 0.f};

#pragma unroll 1
    for (int c = 0; c < 16; ++c) {
      // stage next chunk (or next phase's chunk 0) into the other buffer
      if (c < 15) {
        const char* gp = (const char*)(Ws[L] + (size_t)(c + 1) * 16384);
        char* lp = (char*)Wc[(c + 1) & 1];
#pragma unroll
        for (int j = 0; j < 4; ++j) {
          const int off = wv * 4096 + j * 1024 + lane * 16;
          async_copy16(gp + off, lp + off);
        }
      } else if (L < 3) {
        const char* gp = (const char*)Ws[L + 1];
#pragma unroll
        for (int j = 0; j < 4; ++j) {
          const int off = wv * 4096 + j * 1024 + lane * 16;
          async_copy16(gp + off, (char*)Wc[0] + off);
        }
      } else {
        // theta chunk 0 (8KB)
        async_copy16((const char*)Wtc + tid * 16, (char*)Wc[0] + tid * 16);
      }

      // compute chunk c from Wc[c&1]
      const int kb = c * 64 + g * 16;
      bf16x8 av[4];
#pragma unroll
      for (int m = 0; m < 4; ++m)
        av[m] = *(const bf16x8*)((const char*)hA + rb[m] + (kb ^ am[m]));
      const char* wb = (const char*)Wc[c & 1];
      bf16x8 bv[4];
#pragma unroll
      for (int n = 0; n < 4; ++n) {
        const int col = wv * 64 + n * 16 + l15;
        bv[n] = *(const bf16x8*)(wb + col * 64 + g * 16);
      }
#pragma unroll
      for (int m = 0; m < 4; ++m)
#pragma unroll
        for (int n = 0; n < 4; ++n)
          acc[m][n] = __builtin_amdgcn_mfma_f32_16x16x32_bf16(av[m], bv[n], acc[m][n], 0, 0, 0);
      __syncthreads();
    }

    // epilogue: bias + relu, write h in place
    const float* bias = bs[L];
#pragma unroll
    for (int n = 0; n < 4; ++n) {
      const int col = wv * 64 + n * 16 + l15;
      const float bvv = bias[col];
#pragma unroll
      for (int m = 0; m < 4; ++m)
#pragma unroll
        for (int r = 0; r < 4; ++r) {
          const int row = m * 16 + g * 4 + r;
          const float v = fmaxf(acc[m][n][r] + bvv, 0.f);
          *(unsigned short*)((char*)hA + row * 1024 + ((col * 2) ^ ((row & 7) << 4))) = f2bf(v);
        }
    }
    __syncthreads();
  }

  // ---- theta = h4 @ Wt^T (chunked 8KB DMA stream; wave wv -> 16 cols) ----
  {
    f32x4 tacc[4];
#pragma unroll
    for (int m = 0; m < 4; ++m) tacc[m] = (f32x4){0.f, 0.f, 0.f, 0.f};
#pragma unroll 1
    for (int c = 0; c < 16; ++c) {
      if (c < 15)
        async_copy16((const char*)(Wtc + (size_t)(c + 1) * 4096) + tid * 16,
                     (char*)Wc[(c + 1) & 1] + tid * 16);
      const int kb = c * 64 + g * 16;
      bf16x8 av[4];
#pragma unroll
      for (int m = 0; m < 4; ++m)
        av[m] = *(const bf16x8*)((const char*)hA + rb[m] + (kb ^ am[m]));
      const char* wb = (const char*)Wc[c & 1];
      const int col = wv * 16 + l15;
      const bf16x8 bvt = *(const bf16x8*)(wb + col * 64 + g * 16);
#pragma unroll
      for (int m = 0; m < 4; ++m)
        tacc[m] = __builtin_amdgcn_mfma_f32_16x16x32_bf16(av[m], bvt, tacc[m], 0, 0, 0);
      __syncthreads();
    }
    // theta -> hA as [64][128] bf16, row stride 256B, same swizzle
#pragma unroll
    for (int m = 0; m < 4; ++m)
#pragma unroll
      for (int r = 0; r < 4; ++r) {
        const int row = m * 16 + g * 4 + r;
        const int col = wv * 16 + l15;
        *(unsigned short*)((char*)hA + row * 256 + ((col * 2) ^ ((row & 7) << 4))) =
            f2bf(tacc[m][r]);
      }
  }
  __syncthreads();

  // ---- backcast/forecast: out = theta @ basT^T, basT = [640][128] bf16 ----
  // wave wv -> output cols [wv*80, wv*80+80): 5 frags of 16. Direct L2 reads.
  {
    f32x4 facc[4][5];
#pragma unroll
    for (int m = 0; m < 4; ++m)
#pragma unroll
      for (int n = 0; n < 5; ++n) facc[m][n] = (f32x4){0.f, 0.f, 0.f, 0.f};
    int rb2[4];
#pragma unroll
    for (int m = 0; m < 4; ++m) rb2[m] = (m * 16 + l15) * 256;
    const unsigned short* fp0 = bas + (size_t)(wv * 80 + l15) * 128 + g * 8;
#pragma unroll
    for (int ks = 0; ks < 4; ++ks) {
      bf16x8 bvv[5];
#pragma unroll
      for (int n = 0; n < 5; ++n)
        bvv[n] = *(const bf16x8*)(fp0 + (size_t)(n * 16) * 128 + ks * 32);
      bf16x8 av[4];
      const int kb = ks * 64 + g * 16;
#pragma unroll
      for (int m = 0; m < 4; ++m)
        av[m] = *(const bf16x8*)((const char*)hA + rb2[m] + (kb ^ am[m]));
#pragma unroll
      for (int n = 0; n < 5; ++n)
#pragma unroll
        for (int m = 0; m < 4; ++m)
          facc[m][n] = __builtin_amdgcn_mfma_f32_16x16x32_bf16(av[m], bvv[n], facc[m][n], 0, 0, 0);
    }
    // write fp32 output: backcast [16384][512] then forecast [16384][128]
#pragma unroll
    for (int n = 0; n < 5; ++n) {
      const int col = wv * 80 + n * 16 + l15;
#pragma unroll
      for (int m = 0; m < 4; ++m)
#pragma unroll
        for (int r = 0; r < 4; ++r) {
          const int row = r0 + m * 16 + g * 4 + r;
          const float v = facc[m][n][r];
          if (col < 512)
            out[(size_t)row * 512 + col] = v;
          else
            out[(size_t)BATCH * 512 + (size_t)row * 128 + (col - 512)] = v;
        }
    }
  }
}

// ---------------- launch --------------------------------------------------
extern "C" void kernel_launch(void* const* d_in, const int* in_sizes, int n_in,
                              void* d_out, int out_size, void* d_ws, size_t ws_size,
                              hipStream_t stream) {
  const float* x  = (const float*)d_in[0];
  const float* W1 = (const float*)d_in[1];
  const float* b1 = (const float*)d_in[2];
  const float* W2 = (const float*)d_in[3];
  const float* b2 = (const float*)d_in[4];
  const float* W3 = (const float*)d_in[5];
  const float* b3 = (const float*)d_in[6];
  const float* W4 = (const float*)d_in[7];
  const float* b4 = (const float*)d_in[8];
  const float* Wt = (const float*)d_in[9];

  unsigned short* ws  = (unsigned short*)d_ws;
  unsigned short* W1c = ws;                       // 262144 elems each
  unsigned short* W2c = ws + 262144;
  unsigned short* W3c = ws + 524288;
  unsigned short* W4c = ws + 786432;
  unsigned short* Wtc = ws + 1048576;             // 65536
  unsigned short* bas = ws + 1114112;             // 640*128 = 81920

  prep_kernel<<<864, 256, 0, stream>>>(W1, W2, W3, W4, Wt,
                                       W1c, W2c, W3c, W4c, Wtc, bas);
  fused_nbeats<<<BATCH / ROWS, 512, 0, stream>>>(
      x, W1c, b1, W2c, b2, W3c, b3, W4c, b4, Wtc, bas, (float*)d_out);
}

// Round 4
// 140.056 us; speedup vs baseline: 1.5100x; 1.2527x over previous
//
#include <hip/hip_runtime.h>
#include <hip/hip_bf16.h>
#include <math.h>

// N-BEATS SeasonalityBlock, fused persistent kernel.
// W streamed global->registers (depth-4 prefetch, packed layout, no LDS for W,
// no barriers in k-loop); h[64][512] bf16 in 64KB LDS, XOR-swizzled.
// 256 blocks x 512 threads (8 waves, 1 block/CU); block owns 64 batch rows.

#define BATCH 16384
#define ROWS  64

typedef __bf16 bf16x8 __attribute__((ext_vector_type(8)));
typedef float  f32x4  __attribute__((ext_vector_type(4)));

__device__ __forceinline__ unsigned short f2bf(float f) {
  union { float f; unsigned u; } v; v.f = f;
  unsigned r = v.u + 0x7fff + ((v.u >> 16) & 1);   // RTNE
  return (unsigned short)(r >> 16);
}

// ---------------- prep ----------------------------------------------------
// Packed B layout in 16B units: unit u = (cf*KS + ks)*64 + lane holds
// W[cf*16 + (lane&15)][ks*32 + (lane>>4)*8 + e], e=0..7  (KS = K/32).
// => a wave's load `base[lane]` is 1KB fully contiguous.
__global__ __launch_bounds__(256) void prep_kernel(
    const float* __restrict__ W1, const float* __restrict__ W2,
    const float* __restrict__ W3, const float* __restrict__ W4,
    const float* __restrict__ Wt,
    unsigned short* __restrict__ W1p, unsigned short* __restrict__ W2p,
    unsigned short* __restrict__ W3p, unsigned short* __restrict__ W4p,
    unsigned short* __restrict__ Wtp,
    unsigned short* __restrict__ basp) {
  const int t = blockIdx.x * 256 + threadIdx.x;
  if (t < 139264) {
    const float* src; unsigned short* dst; int u;
    if (t < 131072) {
      const int w = t >> 15; u = t & 32767;
      src = (w == 0) ? W1 : (w == 1) ? W2 : (w == 2) ? W3 : W4;
      dst = (w == 0) ? W1p : (w == 1) ? W2p : (w == 2) ? W3p : W4p;
    } else {
      u = t - 131072; src = Wt; dst = Wtp;
    }
    const int lane = u & 63, ks = (u >> 6) & 15, cf = u >> 10;
    const int col = cf * 16 + (lane & 15);
    const int k0  = ks * 32 + (lane >> 4) * 8;
    const float4* s = (const float4*)(src + (size_t)col * 512 + k0);
    const float4 a = s[0], b = s[1];
    uint4 o;
    o.x = f2bf(a.x) | ((unsigned)f2bf(a.y) << 16);
    o.y = f2bf(a.z) | ((unsigned)f2bf(a.w) << 16);
    o.z = f2bf(b.x) | ((unsigned)f2bf(b.y) << 16);
    o.w = f2bf(b.z) | ((unsigned)f2bf(b.w) << 16);
    ((uint4*)dst)[u] = o;
  } else if (t < 149504) {
    // basis, 640 cols (512 backcast + 128 forecast) x 128 k, KS=4
    const int u = t - 139264;
    const int lane = u & 63, ks = (u >> 6) & 3, cf = u >> 8;
    const int col = cf * 16 + (lane & 15);
    const int r0  = ks * 32 + (lane >> 4) * 8;
    int l, L;
    if (col < 512) { l = col; L = 512; } else { l = col - 512; L = 128; }
    const float w0 = 6.283185307179586f * (float)l / (float)L;
    unsigned short e[8];
#pragma unroll
    for (int i = 0; i < 8; ++i) {
      const int r = r0 + i;
      const float ang = (float)(r >> 1) * w0;
      e[i] = f2bf((r & 1) ? sinf(ang) : cosf(ang));
    }
    uint4 o;
    o.x = e[0] | ((unsigned)e[1] << 16);
    o.y = e[2] | ((unsigned)e[3] << 16);
    o.z = e[4] | ((unsigned)e[5] << 16);
    o.w = e[6] | ((unsigned)e[7] << 16);
    ((uint4*)basp)[u] = o;
  }
}

// ---------------- one FC+ReLU layer, in-place on hA -----------------------
__device__ __forceinline__ void layer512(
    unsigned short* hA, const bf16x8* __restrict__ Wp,
    const float* __restrict__ bias, const int wv, const int lane) {
  const int l15 = lane & 15, g = lane >> 4;
  int rb[4], am[4];
#pragma unroll
  for (int m = 0; m < 4; ++m) {
    const int row = m * 16 + l15;
    rb[m] = row * 1024;
    am[m] = (row & 7) << 4;
  }
  f32x4 acc[4][4];
#pragma unroll
  for (int m = 0; m < 4; ++m)
#pragma unroll
    for (int n = 0; n < 4; ++n) acc[m][n] = (f32x4){0.f, 0.f, 0.f, 0.f};

  // wave's 4 col-frags: cf = wv*4+n, each cf = 16 ks * 64 lanes units
  const bf16x8* base = Wp + (size_t)wv * 4096 + lane;

  bf16x8 bv[4][4];                     // depth-4 rotating prefetch
#pragma unroll
  for (int s = 0; s < 3; ++s)
#pragma unroll
    for (int n = 0; n < 4; ++n) bv[s][n] = base[n * 1024 + s * 64];

#pragma unroll
  for (int ks = 0; ks < 16; ++ks) {
    if (ks < 13) {
#pragma unroll
      for (int n = 0; n < 4; ++n)
        bv[(ks + 3) & 3][n] = base[n * 1024 + (ks + 3) * 64];
    }
    bf16x8 av[4];
    const int kb = ks * 64 + g * 16;
#pragma unroll
    for (int m = 0; m < 4; ++m)
      av[m] = *(const bf16x8*)((const char*)hA + rb[m] + (kb ^ am[m]));
    __builtin_amdgcn_s_setprio(1);
#pragma unroll
    for (int m = 0; m < 4; ++m)
#pragma unroll
      for (int n = 0; n < 4; ++n)
        acc[m][n] = __builtin_amdgcn_mfma_f32_16x16x32_bf16(av[m], bv[ks & 3][n], acc[m][n], 0, 0, 0);
    __builtin_amdgcn_s_setprio(0);
  }

  __syncthreads();   // all waves done reading hA
#pragma unroll
  for (int n = 0; n < 4; ++n) {
    const int col = wv * 64 + n * 16 + l15;
    const float bvv = bias[col];
#pragma unroll
    for (int m = 0; m < 4; ++m)
#pragma unroll
      for (int r = 0; r < 4; ++r) {
        const int row = m * 16 + g * 4 + r;
        const float v = fmaxf(acc[m][n][r] + bvv, 0.f);
        *(unsigned short*)((char*)hA + row * 1024 + ((col * 2) ^ ((row & 7) << 4))) = f2bf(v);
      }
  }
  __syncthreads();   // writes visible
}

// ---------------- fused mega-kernel --------------------------------------
__global__ __launch_bounds__(512, 2) void fused_nbeats(
    const float* __restrict__ x,
    const bf16x8* __restrict__ W1p, const float* __restrict__ b1,
    const bf16x8* __restrict__ W2p, const float* __restrict__ b2,
    const bf16x8* __restrict__ W3p, const float* __restrict__ b3,
    const bf16x8* __restrict__ W4p, const float* __restrict__ b4,
    const bf16x8* __restrict__ Wtp,
    const bf16x8* __restrict__ basp,
    float* __restrict__ out) {
  __shared__ __align__(16) unsigned short hA[ROWS * 512];   // 64 KB

  const int tid  = threadIdx.x;
  const int lane = tid & 63;
  const int wv   = tid >> 6;
  const int l15  = lane & 15, g = lane >> 4;
  const int r0   = blockIdx.x * ROWS;

  // ---- phase 0: x fp32 -> hA bf16 (swizzled rows, 1024B stride) ----
  {
    const float4* xs = (const float4*)(x + (size_t)r0 * 512);
#pragma unroll
    for (int j = 0; j < 16; ++j) {
      const int f = tid + j * 512;          // float4 index in [64][128]
      const int row = f >> 7, c4 = f & 127;
      const float4 v = xs[f];
      uint2 o;
      o.x = f2bf(v.x) | ((unsigned)f2bf(v.y) << 16);
      o.y = f2bf(v.z) | ((unsigned)f2bf(v.w) << 16);
      *(uint2*)((char*)hA + row * 1024 + ((c4 * 8) ^ ((row & 7) << 4))) = o;
    }
  }
  __syncthreads();

  // ---- 4 FC+ReLU layers ----
  layer512(hA, W1p, b1, wv, lane);
  layer512(hA, W2p, b2, wv, lane);
  layer512(hA, W3p, b3, wv, lane);
  layer512(hA, W4p, b4, wv, lane);

  // ---- theta = h4 @ Wt^T (wave wv -> cols wv*16..+15, cf = wv) ----
  {
    int rb[4], am[4];
#pragma unroll
    for (int m = 0; m < 4; ++m) {
      const int row = m * 16 + l15;
      rb[m] = row * 1024;
      am[m] = (row & 7) << 4;
    }
    f32x4 tacc[4];
#pragma unroll
    for (int m = 0; m < 4; ++m) tacc[m] = (f32x4){0.f, 0.f, 0.f, 0.f};
    const bf16x8* tb = Wtp + (size_t)wv * 1024 + lane;
    bf16x8 tv[4];
#pragma unroll
    for (int s = 0; s < 3; ++s) tv[s] = tb[s * 64];
#pragma unroll
    for (int ks = 0; ks < 16; ++ks) {
      if (ks < 13) tv[(ks + 3) & 3] = tb[(ks + 3) * 64];
      bf16x8 av[4];
      const int kb = ks * 64 + g * 16;
#pragma unroll
      for (int m = 0; m < 4; ++m)
        av[m] = *(const bf16x8*)((const char*)hA + rb[m] + (kb ^ am[m]));
      __builtin_amdgcn_s_setprio(1);
#pragma unroll
      for (int m = 0; m < 4; ++m)
        tacc[m] = __builtin_amdgcn_mfma_f32_16x16x32_bf16(av[m], tv[ks & 3], tacc[m], 0, 0, 0);
      __builtin_amdgcn_s_setprio(0);
    }
    __syncthreads();   // h4 reads done; theta overwrites hA[0:16KB]
    // theta -> hA as [64][128] bf16, row stride 256B, same swizzle
#pragma unroll
    for (int m = 0; m < 4; ++m)
#pragma unroll
      for (int r = 0; r < 4; ++r) {
        const int row = m * 16 + g * 4 + r;
        const int col = wv * 16 + l15;
        *(unsigned short*)((char*)hA + row * 256 + ((col * 2) ^ ((row & 7) << 4))) =
            f2bf(tacc[m][r]);
      }
  }
  __syncthreads();

  // ---- backcast/forecast: out = theta @ basT^T (wave wv -> 80 cols) ----
  {
    f32x4 facc[4][5];
#pragma unroll
    for (int m = 0; m < 4; ++m)
#pragma unroll
      for (int n = 0; n < 5; ++n) facc[m][n] = (f32x4){0.f, 0.f, 0.f, 0.f};
    int rb2[4], am2[4];
#pragma unroll
    for (int m = 0; m < 4; ++m) {
      const int row = m * 16 + l15;
      rb2[m] = row * 256;
      am2[m] = (row & 7) << 4;
    }
    const bf16x8* bb = basp + (size_t)wv * 1280 + lane;   // cf=wv*5+n, KS=4
#pragma unroll
    for (int ks = 0; ks < 4; ++ks) {
      bf16x8 bvv[5];
#pragma unroll
      for (int n = 0; n < 5; ++n) bvv[n] = bb[n * 256 + ks * 64];
      bf16x8 av[4];
      const int kb = ks * 64 + g * 16;
#pragma unroll
      for (int m = 0; m < 4; ++m)
        av[m] = *(const bf16x8*)((const char*)hA + rb2[m] + (kb ^ am2[m]));
      __builtin_amdgcn_s_setprio(1);
#pragma unroll
      for (int n = 0; n < 5; ++n)
#pragma unroll
        for (int m = 0; m < 4; ++m)
          facc[m][n] = __builtin_amdgcn_mfma_f32_16x16x32_bf16(av[m], bvv[n], facc[m][n], 0, 0, 0);
      __builtin_amdgcn_s_setprio(0);
    }
    // write fp32 output: backcast [16384][512] then forecast [16384][128]
#pragma unroll
    for (int n = 0; n < 5; ++n) {
      const int col = wv * 80 + n * 16 + l15;
#pragma unroll
      for (int m = 0; m < 4; ++m)
#pragma unroll
        for (int r = 0; r < 4; ++r) {
          const int row = r0 + m * 16 + g * 4 + r;
          const float v = facc[m][n][r];
          if (col < 512)
            out[(size_t)row * 512 + col] = v;
          else
            out[(size_t)BATCH * 512 + (size_t)row * 128 + (col - 512)] = v;
        }
    }
  }
}

// ---------------- launch --------------------------------------------------
extern "C" void kernel_launch(void* const* d_in, const int* in_sizes, int n_in,
                              void* d_out, int out_size, void* d_ws, size_t ws_size,
                              hipStream_t stream) {
  const float* x  = (const float*)d_in[0];
  const float* W1 = (const float*)d_in[1];
  const float* b1 = (const float*)d_in[2];
  const float* W2 = (const float*)d_in[3];
  const float* b2 = (const float*)d_in[4];
  const float* W3 = (const float*)d_in[5];
  const float* b3 = (const float*)d_in[6];
  const float* W4 = (const float*)d_in[7];
  const float* b4 = (const float*)d_in[8];
  const float* Wt = (const float*)d_in[9];

  unsigned short* ws  = (unsigned short*)d_ws;
  unsigned short* W1p = ws;                       // 262144 elems each
  unsigned short* W2p = ws + 262144;
  unsigned short* W3p = ws + 524288;
  unsigned short* W4p = ws + 786432;
  unsigned short* Wtp = ws + 1048576;             // 65536
  unsigned short* basp = ws + 1114112;            // 640*128 = 81920

  prep_kernel<<<584, 256, 0, stream>>>(W1, W2, W3, W4, Wt,
                                       W1p, W2p, W3p, W4p, Wtp, basp);
  fused_nbeats<<<BATCH / ROWS, 512, 0, stream>>>(
      x, (const bf16x8*)W1p, b1, (const bf16x8*)W2p, b2,
      (const bf16x8*)W3p, b3, (const bf16x8*)W4p, b4,
      (const bf16x8*)Wtp, (const bf16x8*)basp, (float*)d_out);
}